// Round 3
// baseline (428.590 us; speedup 1.0000x reference)
//
#include <hip/hip_runtime.h>
#include <hip/hip_bf16.h>

#define BB 4
#define TT 2048
#define CC 768
#define HH 12
#define DD 64
#define MM (BB * TT)      // 8192
#define BH (BB * HH)      // 48

typedef __bf16 bf16_t;
typedef __bf16 bf16x8 __attribute__((ext_vector_type(8)));
typedef __bf16 bf16x4 __attribute__((ext_vector_type(4)));
typedef float f32x4 __attribute__((ext_vector_type(4)));

__device__ __forceinline__ float fast_exp2(float x) {
#if __has_builtin(__builtin_amdgcn_exp2f)
    return __builtin_amdgcn_exp2f(x);
#else
    return exp2f(x);
#endif
}

__device__ __forceinline__ uint32_t pk2(float lo, float hi) {
    bf16_t l = (bf16_t)lo, h = (bf16_t)hi;
    uint16_t lu = __builtin_bit_cast(uint16_t, l);
    uint16_t hu = __builtin_bit_cast(uint16_t, h);
    return ((uint32_t)hu << 16) | lu;
}

// ---------------------------------------------------------------- convert f32 -> bf16
__global__ void cvt_f32_bf16(const float* __restrict__ in, bf16_t* __restrict__ out, int n4) {
    int tid = blockIdx.x * blockDim.x + threadIdx.x;
    if (tid >= n4) return;
    float4 v = ((const float4*)in)[tid];
    bf16x4 o;
    o[0] = (bf16_t)v.x; o[1] = (bf16_t)v.y; o[2] = (bf16_t)v.z; o[3] = (bf16_t)v.w;
    ((bf16x4*)out)[tid] = o;
}

// ---------------------------------------------------------------- transpose + convert: W[K][N] f32 -> WT[N][K] bf16
__global__ void transpose_cvt(const float* __restrict__ W, bf16_t* __restrict__ WT, int K, int N) {
    __shared__ bf16_t tile[32][33];
    int k0 = blockIdx.x * 32, n0 = blockIdx.y * 32;
    int tx = threadIdx.x, ty = threadIdx.y;   // block (32, 8)
#pragma unroll
    for (int r = 0; r < 4; ++r) {
        int kl = ty * 4 + r;
        tile[kl][tx] = (bf16_t)W[(size_t)(k0 + kl) * N + n0 + tx];
    }
    __syncthreads();
#pragma unroll
    for (int r = 0; r < 4; ++r) {
        int nl = ty * 4 + r;
        WT[(size_t)(n0 + nl) * K + k0 + tx] = tile[tx][nl];
    }
}

// ---------------------------------------------------------------- GEMM: C[M][N] = A[M][768] @ BT[N][768]^T + bias
template <bool OUT_BF16>
__global__ __launch_bounds__(256, 2) void gemm_bias(
        const bf16_t* __restrict__ A, const bf16_t* __restrict__ BT,
        const float* __restrict__ bias, void* __restrict__ Cout, int N) {
    const int K = 768;
    __shared__ bf16_t As[128 * 40];
    __shared__ bf16_t Bs[128 * 40];
    int tid = threadIdx.x;
    int wv = tid >> 6, lane = tid & 63, c = lane & 15, quad = lane >> 4;
    int wm = (wv >> 1) * 64, wn = (wv & 1) * 64;
    int m0 = blockIdx.x * 128, n0 = blockIdx.y * 128;
    int lr = tid >> 2, lc = (tid & 3) * 8;
    const bf16_t* Ag = A + (size_t)(m0 + lr) * K + lc;
    const bf16_t* Bg = BT + (size_t)(n0 + lr) * K + lc;

    f32x4 acc[4][4] = {};
    for (int k0 = 0; k0 < K; k0 += 32) {
        uint4 a0 = *(const uint4*)(Ag + k0);
        uint4 a1 = *(const uint4*)(Ag + (size_t)64 * K + k0);
        uint4 b0 = *(const uint4*)(Bg + k0);
        uint4 b1 = *(const uint4*)(Bg + (size_t)64 * K + k0);
        __syncthreads();
        *(uint4*)&As[lr * 40 + lc] = a0;
        *(uint4*)&As[(lr + 64) * 40 + lc] = a1;
        *(uint4*)&Bs[lr * 40 + lc] = b0;
        *(uint4*)&Bs[(lr + 64) * 40 + lc] = b1;
        __syncthreads();
        bf16x8 af[4], bf[4];
#pragma unroll
        for (int i = 0; i < 4; ++i) af[i] = *(const bf16x8*)&As[(wm + i * 16 + c) * 40 + quad * 8];
#pragma unroll
        for (int j = 0; j < 4; ++j) bf[j] = *(const bf16x8*)&Bs[(wn + j * 16 + c) * 40 + quad * 8];
#pragma unroll
        for (int i = 0; i < 4; ++i)
#pragma unroll
            for (int j = 0; j < 4; ++j)
                acc[i][j] = __builtin_amdgcn_mfma_f32_16x16x32_bf16(af[i], bf[j], acc[i][j], 0, 0, 0);
    }
#pragma unroll
    for (int j = 0; j < 4; ++j) {
        int col = n0 + wn + j * 16 + c;
        float bv = bias[col];
#pragma unroll
        for (int i = 0; i < 4; ++i) {
            int row = m0 + wm + i * 16 + quad * 4;
#pragma unroll
            for (int r = 0; r < 4; ++r) {
                float v = acc[i][j][r] + bv;
                if (OUT_BF16) ((bf16_t*)Cout)[(size_t)(row + r) * N + col] = (bf16_t)v;
                else          ((float*)Cout)[(size_t)(row + r) * N + col] = v;
            }
        }
    }
}

// ---------------------------------------------------------------- rotary: qkv -> Q,K [BH][T][64] bf16
__global__ void rotary_qk(const bf16_t* __restrict__ qkv, bf16_t* __restrict__ Q, bf16_t* __restrict__ Kc) {
    int tid = blockIdx.x * blockDim.x + threadIdx.x;   // MM*HH*32 threads
    int i = tid & 31;
    int rem = tid >> 5;
    int h = rem % HH;
    int row = rem / HH;            // b*T + t
    int b = row >> 11, t = row & (TT - 1);
    const bf16_t* base = qkv + (size_t)row * (3 * CC) + h * DD + i;
    float q1 = (float)base[0],  q2 = (float)base[32];
    float k1 = (float)base[CC], k2 = (float)base[CC + 32];
    float inv = powf(10000.0f, -(float)i * (1.0f / 32.0f));
    float fr = (float)t * inv;
    float cs = cosf(fr), sn = sinf(fr);
    const float scale = 0.125f * 1.44269504088896f;    // 1/sqrt(64) * log2(e)
    size_t o = ((size_t)(b * HH + h) * TT + t) * DD + i;
    Q[o]      = (bf16_t)((q1 * cs + q2 * sn) * scale);
    Q[o + 32] = (bf16_t)((-q1 * sn + q2 * cs) * scale);
    Kc[o]      = (bf16_t)(k1 * cs + k2 * sn);
    Kc[o + 32] = (bf16_t)(-k1 * sn + k2 * cs);
}

// ---------------------------------------------------------------- V transpose: qkv v-part -> Vt [BH][64][T] bf16
__global__ void vtrans(const bf16_t* __restrict__ qkv, bf16_t* __restrict__ Vt) {
    int bh = blockIdx.x;
    int t0 = blockIdx.y * 64;
    int b = bh / HH, h = bh % HH;
    __shared__ bf16_t tile[64][66];
    int tx = threadIdx.x & 63, ty = threadIdx.x >> 6;
#pragma unroll
    for (int r = 0; r < 16; ++r) {
        int tl = ty * 16 + r;
        tile[tl][tx] = qkv[(size_t)(b * TT + t0 + tl) * (3 * CC) + 2 * CC + h * DD + tx];
    }
    __syncthreads();
#pragma unroll
    for (int r = 0; r < 16; ++r) {
        int dl = ty * 16 + r;
        Vt[((size_t)bh * DD + dl) * TT + t0 + tx] = tile[tx][dl];
    }
}

// ---------------------------------------------------------------- flash attention, K-split partial version
// One wave per (bh, 32-query tile, chunk of <=16 key-steps). 7680 waves total.
// Partial O^T (unnormalized, f32) and partial row-sums l are atomicAdd'd into
// Yf [MM][CC] f32 and Lf [BH][TT] f32 (both pre-zeroed). No-max exp2 softmax
// makes partials purely associative.
__global__ __launch_bounds__(64, 4) void flash_attn_split(
        const bf16_t* __restrict__ Q, const bf16_t* __restrict__ Kc,
        const bf16_t* __restrict__ Vt, float* __restrict__ Yf, float* __restrict__ Lf) {
    int blk = blockIdx.x;
    int bh = blk % BH;
    int j = 159 - (blk / BH);      // heavy chunks (large qt, full 16 steps) dispatch first
    int qt, chunk;
    if (j < 16)      { qt = j;                  chunk = 0; }
    else if (j < 48) { qt = 16 + ((j - 16) >> 1); chunk = (j - 16) & 1; }
    else if (j < 96) { qt = 32 + (j - 48) / 3;    chunk = (j - 48) % 3; }
    else             { qt = 48 + ((j - 96) >> 2); chunk = (j - 96) & 3; }
    int sc = chunk * 16;
    int ec = min(sc + 16, qt + 1);

    int b = bh / HH, h = bh - b * HH;
    int lane = threadIdx.x;
    int c = lane & 15, quad = lane >> 4;
    int qb = qt * 32;
    const bf16_t* Qg = Q + ((size_t)bh * TT + qb) * DD;
    const bf16_t* Kg = Kc + (size_t)bh * TT * DD;
    const bf16_t* Vg = Vt + (size_t)bh * DD * TT;

    bf16x8 qf[2][2];
#pragma unroll
    for (int s = 0; s < 2; ++s)
#pragma unroll
        for (int ch = 0; ch < 2; ++ch)
            qf[s][ch] = *(const bf16x8*)(Qg + (s * 16 + c) * DD + ch * 32 + quad * 8);

    f32x4 O[2][4] = {};          // O^T: col=query=c, row=d=nt*16+quad*4+r
    float lsum[2] = {0.0f, 0.0f};

    bf16x8 kf[2][2], vf[4];
    auto loadKV = [&](int kb, bf16x8 kfo[2][2], bf16x8 vfo[4]) {
#pragma unroll
        for (int t2 = 0; t2 < 2; ++t2)
#pragma unroll
            for (int ch = 0; ch < 2; ++ch)
                kfo[t2][ch] = *(const bf16x8*)(Kg + (kb + t2 * 16 + c) * DD + ch * 32 + quad * 8);
#pragma unroll
        for (int nt = 0; nt < 4; ++nt)
            vfo[nt] = *(const bf16x8*)(Vg + (nt * 16 + c) * TT + kb + quad * 8);
    };

    int lane_lo = c + ((quad & 1) << 5);
    int lane_hi = lane_lo + 16;
    bool lowq = (quad < 2);

    auto step = [&](bool masked) {
        f32x4 st[2][2] = {};
#pragma unroll
        for (int s = 0; s < 2; ++s)
#pragma unroll
            for (int t2 = 0; t2 < 2; ++t2) {
                st[s][t2] = __builtin_amdgcn_mfma_f32_16x16x32_bf16(kf[t2][0], qf[s][0], st[s][t2], 0, 0, 0);
                st[s][t2] = __builtin_amdgcn_mfma_f32_16x16x32_bf16(kf[t2][1], qf[s][1], st[s][t2], 0, 0, 0);
            }
#pragma unroll
        for (int s = 0; s < 2; ++s) {
            float pv[2][4];
#pragma unroll
            for (int t2 = 0; t2 < 2; ++t2)
#pragma unroll
                for (int r = 0; r < 4; ++r) {
                    float p = fast_exp2(st[s][t2][r]);
                    if (masked) {
                        int keyl = t2 * 16 + quad * 4 + r;
                        if (keyl > s * 16 + c) p = 0.0f;
                    }
                    pv[t2][r] = p;
                }
            lsum[s] += ((pv[0][0] + pv[0][1]) + (pv[0][2] + pv[0][3]))
                     + ((pv[1][0] + pv[1][1]) + (pv[1][2] + pv[1][3]));
            uint32_t pk0a = pk2(pv[0][0], pv[0][1]), pk0b = pk2(pv[0][2], pv[0][3]);
            uint32_t pk1a = pk2(pv[1][0], pv[1][1]), pk1b = pk2(pv[1][2], pv[1][3]);
            union { uint32_t u[4]; bf16x8 v; } pf;
            {
                uint32_t x0 = (uint32_t)__shfl((int)pk0a, lane_lo);
                uint32_t y0 = (uint32_t)__shfl((int)pk1a, lane_lo);
                pf.u[0] = lowq ? x0 : y0;
                uint32_t x1 = (uint32_t)__shfl((int)pk0b, lane_lo);
                uint32_t y1 = (uint32_t)__shfl((int)pk1b, lane_lo);
                pf.u[1] = lowq ? x1 : y1;
                uint32_t x2 = (uint32_t)__shfl((int)pk0a, lane_hi);
                uint32_t y2 = (uint32_t)__shfl((int)pk1a, lane_hi);
                pf.u[2] = lowq ? x2 : y2;
                uint32_t x3 = (uint32_t)__shfl((int)pk0b, lane_hi);
                uint32_t y3 = (uint32_t)__shfl((int)pk1b, lane_hi);
                pf.u[3] = lowq ? x3 : y3;
            }
#pragma unroll
            for (int nt = 0; nt < 4; ++nt)
                O[s][nt] = __builtin_amdgcn_mfma_f32_16x16x32_bf16(vf[nt], pf.v, O[s][nt], 0, 0, 0);
        }
    };

    loadKV(sc * 32, kf, vf);
    for (int kt = sc; kt < ec - 1; ++kt) {
        bf16x8 kn[2][2], vn[4];
        loadKV((kt + 1) * 32, kn, vn);
        step(false);
#pragma unroll
        for (int t2 = 0; t2 < 2; ++t2)
#pragma unroll
            for (int ch = 0; ch < 2; ++ch) kf[t2][ch] = kn[t2][ch];
#pragma unroll
        for (int nt = 0; nt < 4; ++nt) vf[nt] = vn[nt];
    }
    step(ec - 1 == qt);   // only the true diagonal tile masks

    // epilogue: atomic-accumulate partial l and O^T
#pragma unroll
    for (int s = 0; s < 2; ++s) {
        float l = lsum[s];
        l += __shfl_xor(l, 16);
        l += __shfl_xor(l, 32);
        if (quad == 0) atomicAdd(&Lf[(size_t)bh * TT + qb + s * 16 + c], l);
        size_t row = (size_t)(b * TT + qb + s * 16 + c) * CC + h * DD;
#pragma unroll
        for (int nt = 0; nt < 4; ++nt)
#pragma unroll
            for (int r = 0; r < 4; ++r)
                atomicAdd(&Yf[row + nt * 16 + quad * 4 + r], O[s][nt][r]);
    }
}

// ---------------------------------------------------------------- combine: Yb = bf16(Yf / L)
__global__ void combine_norm(const float* __restrict__ Yf, const float* __restrict__ Lf,
                             bf16_t* __restrict__ Yb) {
    int tid = blockIdx.x * blockDim.x + threadIdx.x;   // MM*CC/8 threads
    int idx = tid * 8;
    int row = idx / CC;            // b*T + t
    int cidx = idx - row * CC;
    int h = cidx >> 6;
    int b = row >> 11, t = row & (TT - 1);
    float inv = 1.0f / Lf[(size_t)(b * HH + h) * TT + t];
    float4 v0 = *(const float4*)(Yf + idx);
    float4 v1 = *(const float4*)(Yf + idx + 4);
    bf16x8 o;
    o[0] = (bf16_t)(v0.x * inv); o[1] = (bf16_t)(v0.y * inv);
    o[2] = (bf16_t)(v0.z * inv); o[3] = (bf16_t)(v0.w * inv);
    o[4] = (bf16_t)(v1.x * inv); o[5] = (bf16_t)(v1.y * inv);
    o[6] = (bf16_t)(v1.z * inv); o[7] = (bf16_t)(v1.w * inv);
    *(bf16x8*)(Yb + idx) = o;
}

// ---------------------------------------------------------------- launch
extern "C" void kernel_launch(void* const* d_in, const int* in_sizes, int n_in,
                              void* d_out, int out_size, void* d_ws, size_t ws_size,
                              hipStream_t stream) {
    const float* x      = (const float*)d_in[0];
    const float* W_attn = (const float*)d_in[1];
    const float* b_attn = (const float*)d_in[2];
    const float* W_proj = (const float*)d_in[3];
    const float* b_proj = (const float*)d_in[4];
    float* out = (float*)d_out;

    unsigned char* ws = (unsigned char*)d_ws;
    size_t off = 0;
    auto alloc = [&](size_t bytes) { void* p = ws + off; off += (bytes + 255) & ~(size_t)255; return p; };
    bf16_t* xb  = (bf16_t*)alloc((size_t)MM * CC * 2);
    bf16_t* WaT = (bf16_t*)alloc((size_t)3 * CC * CC * 2);
    bf16_t* WpT = (bf16_t*)alloc((size_t)CC * CC * 2);
    bf16_t* qkv = (bf16_t*)alloc((size_t)MM * 3 * CC * 2);
    bf16_t* Qh  = (bf16_t*)alloc((size_t)BH * TT * DD * 2);
    bf16_t* Kh  = (bf16_t*)alloc((size_t)BH * TT * DD * 2);
    bf16_t* Vt  = (bf16_t*)alloc((size_t)BH * DD * TT * 2);
    bf16_t* Yb  = (bf16_t*)alloc((size_t)MM * CC * 2);
    float*  Yf  = (float*)alloc((size_t)MM * CC * 4);
    float*  Lf  = (float*)alloc((size_t)BH * TT * 4);

    hipMemsetAsync(Yf, 0, (size_t)MM * CC * 4, stream);
    hipMemsetAsync(Lf, 0, (size_t)BH * TT * 4, stream);

    cvt_f32_bf16<<<(MM * CC / 4 + 255) / 256, 256, 0, stream>>>(x, xb, MM * CC / 4);
    transpose_cvt<<<dim3(CC / 32, 3 * CC / 32), dim3(32, 8), 0, stream>>>(W_attn, WaT, CC, 3 * CC);
    transpose_cvt<<<dim3(CC / 32, CC / 32), dim3(32, 8), 0, stream>>>(W_proj, WpT, CC, CC);
    gemm_bias<true><<<dim3(MM / 128, 3 * CC / 128), 256, 0, stream>>>(xb, WaT, b_attn, qkv, 3 * CC);
    rotary_qk<<<(MM * HH * 32) / 256, 256, 0, stream>>>(qkv, Qh, Kh);
    vtrans<<<dim3(BH, TT / 64), 256, 0, stream>>>(qkv, Vt);
    flash_attn_split<<<dim3(BH * 160), 64, 0, stream>>>(Qh, Kh, Vt, Yf, Lf);
    combine_norm<<<(MM * CC / 8) / 256, 256, 0, stream>>>(Yf, Lf, Yb);
    gemm_bias<false><<<dim3(MM / 128, CC / 128), 256, 0, stream>>>(Yb, WpT, b_proj, out, CC);
}

// Round 4
// 294.188 us; speedup vs baseline: 1.4569x; 1.4569x over previous
//
#include <hip/hip_runtime.h>
#include <hip/hip_bf16.h>

#define BB 4
#define TT 2048
#define CC 768
#define HH 12
#define DD 64
#define MM (BB * TT)      // 8192
#define BH (BB * HH)      // 48

typedef __bf16 bf16_t;
typedef __bf16 bf16x8 __attribute__((ext_vector_type(8)));
typedef __bf16 bf16x4 __attribute__((ext_vector_type(4)));
typedef float f32x4 __attribute__((ext_vector_type(4)));

__device__ __forceinline__ float fast_exp2(float x) {
#if __has_builtin(__builtin_amdgcn_exp2f)
    return __builtin_amdgcn_exp2f(x);
#else
    return exp2f(x);
#endif
}

__device__ __forceinline__ uint32_t pk2(float lo, float hi) {
    bf16_t l = (bf16_t)lo, h = (bf16_t)hi;
    uint16_t lu = __builtin_bit_cast(uint16_t, l);
    uint16_t hu = __builtin_bit_cast(uint16_t, h);
    return ((uint32_t)hu << 16) | lu;
}

// ---------------------------------------------------------------- convert f32 -> bf16
__global__ void cvt_f32_bf16(const float* __restrict__ in, bf16_t* __restrict__ out, int n4) {
    int tid = blockIdx.x * blockDim.x + threadIdx.x;
    if (tid >= n4) return;
    float4 v = ((const float4*)in)[tid];
    bf16x4 o;
    o[0] = (bf16_t)v.x; o[1] = (bf16_t)v.y; o[2] = (bf16_t)v.z; o[3] = (bf16_t)v.w;
    ((bf16x4*)out)[tid] = o;
}

// ---------------------------------------------------------------- transpose + convert: W[K][N] f32 -> WT[N][K] bf16
__global__ void transpose_cvt(const float* __restrict__ W, bf16_t* __restrict__ WT, int K, int N) {
    __shared__ bf16_t tile[32][33];
    int k0 = blockIdx.x * 32, n0 = blockIdx.y * 32;
    int tx = threadIdx.x, ty = threadIdx.y;   // block (32, 8)
#pragma unroll
    for (int r = 0; r < 4; ++r) {
        int kl = ty * 4 + r;
        tile[kl][tx] = (bf16_t)W[(size_t)(k0 + kl) * N + n0 + tx];
    }
    __syncthreads();
#pragma unroll
    for (int r = 0; r < 4; ++r) {
        int nl = ty * 4 + r;
        WT[(size_t)(n0 + nl) * K + k0 + tx] = tile[tx][nl];
    }
}

// ---------------------------------------------------------------- GEMM: C[M][N] = A[M][768] @ BT[N][768]^T + bias
template <bool OUT_BF16>
__global__ __launch_bounds__(256, 2) void gemm_bias(
        const bf16_t* __restrict__ A, const bf16_t* __restrict__ BT,
        const float* __restrict__ bias, void* __restrict__ Cout, int N) {
    const int K = 768;
    __shared__ bf16_t As[128 * 40];
    __shared__ bf16_t Bs[128 * 40];
    int tid = threadIdx.x;
    int wv = tid >> 6, lane = tid & 63, c = lane & 15, quad = lane >> 4;
    int wm = (wv >> 1) * 64, wn = (wv & 1) * 64;
    int m0 = blockIdx.x * 128, n0 = blockIdx.y * 128;
    int lr = tid >> 2, lc = (tid & 3) * 8;
    const bf16_t* Ag = A + (size_t)(m0 + lr) * K + lc;
    const bf16_t* Bg = BT + (size_t)(n0 + lr) * K + lc;

    f32x4 acc[4][4] = {};
    for (int k0 = 0; k0 < K; k0 += 32) {
        uint4 a0 = *(const uint4*)(Ag + k0);
        uint4 a1 = *(const uint4*)(Ag + (size_t)64 * K + k0);
        uint4 b0 = *(const uint4*)(Bg + k0);
        uint4 b1 = *(const uint4*)(Bg + (size_t)64 * K + k0);
        __syncthreads();
        *(uint4*)&As[lr * 40 + lc] = a0;
        *(uint4*)&As[(lr + 64) * 40 + lc] = a1;
        *(uint4*)&Bs[lr * 40 + lc] = b0;
        *(uint4*)&Bs[(lr + 64) * 40 + lc] = b1;
        __syncthreads();
        bf16x8 af[4], bf[4];
#pragma unroll
        for (int i = 0; i < 4; ++i) af[i] = *(const bf16x8*)&As[(wm + i * 16 + c) * 40 + quad * 8];
#pragma unroll
        for (int j = 0; j < 4; ++j) bf[j] = *(const bf16x8*)&Bs[(wn + j * 16 + c) * 40 + quad * 8];
#pragma unroll
        for (int i = 0; i < 4; ++i)
#pragma unroll
            for (int j = 0; j < 4; ++j)
                acc[i][j] = __builtin_amdgcn_mfma_f32_16x16x32_bf16(af[i], bf[j], acc[i][j], 0, 0, 0);
    }
#pragma unroll
    for (int j = 0; j < 4; ++j) {
        int col = n0 + wn + j * 16 + c;
        float bv = bias[col];
#pragma unroll
        for (int i = 0; i < 4; ++i) {
            int row = m0 + wm + i * 16 + quad * 4;
#pragma unroll
            for (int r = 0; r < 4; ++r) {
                float v = acc[i][j][r] + bv;
                if (OUT_BF16) ((bf16_t*)Cout)[(size_t)(row + r) * N + col] = (bf16_t)v;
                else          ((float*)Cout)[(size_t)(row + r) * N + col] = v;
            }
        }
    }
}

// ---------------------------------------------------------------- rotary: qkv -> Q,K [BH][T][64] bf16
__global__ void rotary_qk(const bf16_t* __restrict__ qkv, bf16_t* __restrict__ Q, bf16_t* __restrict__ Kc) {
    int tid = blockIdx.x * blockDim.x + threadIdx.x;   // MM*HH*32 threads
    int i = tid & 31;
    int rem = tid >> 5;
    int h = rem % HH;
    int row = rem / HH;            // b*T + t
    int b = row >> 11, t = row & (TT - 1);
    const bf16_t* base = qkv + (size_t)row * (3 * CC) + h * DD + i;
    float q1 = (float)base[0],  q2 = (float)base[32];
    float k1 = (float)base[CC], k2 = (float)base[CC + 32];
    float inv = powf(10000.0f, -(float)i * (1.0f / 32.0f));
    float fr = (float)t * inv;
    float cs = cosf(fr), sn = sinf(fr);
    const float scale = 0.125f * 1.44269504088896f;    // 1/sqrt(64) * log2(e)
    size_t o = ((size_t)(b * HH + h) * TT + t) * DD + i;
    Q[o]      = (bf16_t)((q1 * cs + q2 * sn) * scale);
    Q[o + 32] = (bf16_t)((-q1 * sn + q2 * cs) * scale);
    Kc[o]      = (bf16_t)(k1 * cs + k2 * sn);
    Kc[o + 32] = (bf16_t)(-k1 * sn + k2 * cs);
}

// ---------------------------------------------------------------- V transpose: qkv v-part -> Vt [BH][64][T] bf16
__global__ void vtrans(const bf16_t* __restrict__ qkv, bf16_t* __restrict__ Vt) {
    int bh = blockIdx.x;
    int t0 = blockIdx.y * 64;
    int b = bh / HH, h = bh % HH;
    __shared__ bf16_t tile[64][66];
    int tx = threadIdx.x & 63, ty = threadIdx.x >> 6;
#pragma unroll
    for (int r = 0; r < 16; ++r) {
        int tl = ty * 16 + r;
        tile[tl][tx] = qkv[(size_t)(b * TT + t0 + tl) * (3 * CC) + 2 * CC + h * DD + tx];
    }
    __syncthreads();
#pragma unroll
    for (int r = 0; r < 16; ++r) {
        int dl = ty * 16 + r;
        Vt[((size_t)bh * DD + dl) * TT + t0 + tx] = tile[tx][dl];
    }
}

// ---------------------------------------------------------------- flash attention, XCD-pinned heads
// grid 768 blocks x 256 thr (4 waves, no barrier, no LDS). xcd = blk%8 owns
// 6 heads (K+V = 3MB -> L2-resident). Block covers 128 queries; its 4 waves
// walk the same K/V tile sequence so fragment loads L1-hit after wave 0.
// Per-wave math identical to R2's verified kernel (S^T via mfma(K,Q),
// no-max exp2 softmax, bpermute P-transform, O^T via mfma(V,P)).
__global__ __launch_bounds__(256, 3) void flash_attn(
        const bf16_t* __restrict__ Q, const bf16_t* __restrict__ Kc,
        const bf16_t* __restrict__ Vt, bf16_t* __restrict__ Y) {
    int blk = blockIdx.x;
    int xcd = blk & 7;
    int g = blk >> 3;                 // 0..95
    int bh = xcd * 6 + g % 6;
    int qt128 = 15 - g / 6;           // heavy 128-query tiles dispatch first
    int wv = threadIdx.x >> 6, lane = threadIdx.x & 63;
    int b = bh / HH, h = bh - b * HH;
    int c = lane & 15, quad = lane >> 4;
    int qb = qt128 * 128 + wv * 32;
    const bf16_t* Qg = Q + ((size_t)bh * TT + qb) * DD;
    const bf16_t* Kg = Kc + (size_t)bh * TT * DD;
    const bf16_t* Vg = Vt + (size_t)bh * DD * TT;

    bf16x8 qf[2][2];
#pragma unroll
    for (int s = 0; s < 2; ++s)
#pragma unroll
        for (int ch = 0; ch < 2; ++ch)
            qf[s][ch] = *(const bf16x8*)(Qg + (s * 16 + c) * DD + ch * 32 + quad * 8);

    f32x4 O[2][4] = {};          // O^T: col=query=c, row=d=nt*16+quad*4+r
    float lsum[2] = {0.0f, 0.0f};

    bf16x8 kf[2][2], vf[4];
    auto loadKV = [&](int kb, bf16x8 kfo[2][2], bf16x8 vfo[4]) {
#pragma unroll
        for (int t2 = 0; t2 < 2; ++t2)
#pragma unroll
            for (int ch = 0; ch < 2; ++ch)
                kfo[t2][ch] = *(const bf16x8*)(Kg + (kb + t2 * 16 + c) * DD + ch * 32 + quad * 8);
#pragma unroll
        for (int nt = 0; nt < 4; ++nt)
            vfo[nt] = *(const bf16x8*)(Vg + (nt * 16 + c) * TT + kb + quad * 8);
    };

    int lane_lo = c + ((quad & 1) << 5);
    int lane_hi = lane_lo + 16;
    bool lowq = (quad < 2);

    auto step = [&](bool masked) {
        f32x4 st[2][2] = {};
#pragma unroll
        for (int s = 0; s < 2; ++s)
#pragma unroll
            for (int t2 = 0; t2 < 2; ++t2) {
                st[s][t2] = __builtin_amdgcn_mfma_f32_16x16x32_bf16(kf[t2][0], qf[s][0], st[s][t2], 0, 0, 0);
                st[s][t2] = __builtin_amdgcn_mfma_f32_16x16x32_bf16(kf[t2][1], qf[s][1], st[s][t2], 0, 0, 0);
            }
#pragma unroll
        for (int s = 0; s < 2; ++s) {
            float pv[2][4];
#pragma unroll
            for (int t2 = 0; t2 < 2; ++t2)
#pragma unroll
                for (int r = 0; r < 4; ++r) {
                    float p = fast_exp2(st[s][t2][r]);
                    if (masked) {
                        int keyl = t2 * 16 + quad * 4 + r;
                        if (keyl > s * 16 + c) p = 0.0f;
                    }
                    pv[t2][r] = p;
                }
            lsum[s] += ((pv[0][0] + pv[0][1]) + (pv[0][2] + pv[0][3]))
                     + ((pv[1][0] + pv[1][1]) + (pv[1][2] + pv[1][3]));
            uint32_t pk0a = pk2(pv[0][0], pv[0][1]), pk0b = pk2(pv[0][2], pv[0][3]);
            uint32_t pk1a = pk2(pv[1][0], pv[1][1]), pk1b = pk2(pv[1][2], pv[1][3]);
            union { uint32_t u[4]; bf16x8 v; } pf;
            {
                uint32_t x0 = (uint32_t)__shfl((int)pk0a, lane_lo);
                uint32_t y0 = (uint32_t)__shfl((int)pk1a, lane_lo);
                pf.u[0] = lowq ? x0 : y0;
                uint32_t x1 = (uint32_t)__shfl((int)pk0b, lane_lo);
                uint32_t y1 = (uint32_t)__shfl((int)pk1b, lane_lo);
                pf.u[1] = lowq ? x1 : y1;
                uint32_t x2 = (uint32_t)__shfl((int)pk0a, lane_hi);
                uint32_t y2 = (uint32_t)__shfl((int)pk1a, lane_hi);
                pf.u[2] = lowq ? x2 : y2;
                uint32_t x3 = (uint32_t)__shfl((int)pk0b, lane_hi);
                uint32_t y3 = (uint32_t)__shfl((int)pk1b, lane_hi);
                pf.u[3] = lowq ? x3 : y3;
            }
#pragma unroll
            for (int nt = 0; nt < 4; ++nt)
                O[s][nt] = __builtin_amdgcn_mfma_f32_16x16x32_bf16(vf[nt], pf.v, O[s][nt], 0, 0, 0);
        }
    };

    int nkt = qb / 32 + 1;
    loadKV(0, kf, vf);
    int kb = 0;
    for (int kt = 0; kt + 1 < nkt; ++kt) {
        bf16x8 kn[2][2], vn[4];
        loadKV(kb + 32, kn, vn);
        step(false);
#pragma unroll
        for (int t2 = 0; t2 < 2; ++t2)
#pragma unroll
            for (int ch = 0; ch < 2; ++ch) kf[t2][ch] = kn[t2][ch];
#pragma unroll
        for (int nt = 0; nt < 4; ++nt) vf[nt] = vn[nt];
        kb += 32;
    }
    step(true);   // diagonal tile

    // final: reduce l across quads (queries live in c), normalize, write O^T
#pragma unroll
    for (int s = 0; s < 2; ++s) {
        float l = lsum[s];
        l += __shfl_xor(l, 16);
        l += __shfl_xor(l, 32);
        float inv_l = 1.0f / l;
        int row = b * TT + qb + s * 16 + c;
#pragma unroll
        for (int nt = 0; nt < 4; ++nt) {
            bf16x4 ov;
#pragma unroll
            for (int r = 0; r < 4; ++r) ov[r] = (bf16_t)(O[s][nt][r] * inv_l);
            *(bf16x4*)(Y + (size_t)row * CC + h * DD + nt * 16 + quad * 4) = ov;
        }
    }
}

// ---------------------------------------------------------------- launch
extern "C" void kernel_launch(void* const* d_in, const int* in_sizes, int n_in,
                              void* d_out, int out_size, void* d_ws, size_t ws_size,
                              hipStream_t stream) {
    const float* x      = (const float*)d_in[0];
    const float* W_attn = (const float*)d_in[1];
    const float* b_attn = (const float*)d_in[2];
    const float* W_proj = (const float*)d_in[3];
    const float* b_proj = (const float*)d_in[4];
    float* out = (float*)d_out;

    unsigned char* ws = (unsigned char*)d_ws;
    size_t off = 0;
    auto alloc = [&](size_t bytes) { void* p = ws + off; off += (bytes + 255) & ~(size_t)255; return p; };
    bf16_t* xb  = (bf16_t*)alloc((size_t)MM * CC * 2);
    bf16_t* WaT = (bf16_t*)alloc((size_t)3 * CC * CC * 2);
    bf16_t* WpT = (bf16_t*)alloc((size_t)CC * CC * 2);
    bf16_t* qkv = (bf16_t*)alloc((size_t)MM * 3 * CC * 2);
    bf16_t* Qh  = (bf16_t*)alloc((size_t)BH * TT * DD * 2);
    bf16_t* Kh  = (bf16_t*)alloc((size_t)BH * TT * DD * 2);
    bf16_t* Vt  = (bf16_t*)alloc((size_t)BH * DD * TT * 2);
    bf16_t* Yb  = (bf16_t*)alloc((size_t)MM * CC * 2);

    cvt_f32_bf16<<<(MM * CC / 4 + 255) / 256, 256, 0, stream>>>(x, xb, MM * CC / 4);
    transpose_cvt<<<dim3(CC / 32, 3 * CC / 32), dim3(32, 8), 0, stream>>>(W_attn, WaT, CC, 3 * CC);
    transpose_cvt<<<dim3(CC / 32, CC / 32), dim3(32, 8), 0, stream>>>(W_proj, WpT, CC, CC);
    gemm_bias<true><<<dim3(MM / 128, 3 * CC / 128), 256, 0, stream>>>(xb, WaT, b_attn, qkv, 3 * CC);
    rotary_qk<<<(MM * HH * 32) / 256, 256, 0, stream>>>(qkv, Qh, Kh);
    vtrans<<<dim3(BH, TT / 64), 256, 0, stream>>>(qkv, Vt);
    flash_attn<<<dim3(768), 256, 0, stream>>>(Qh, Kh, Vt, Yb);
    gemm_bias<false><<<dim3(MM / 128, CC / 128), 256, 0, stream>>>(Yb, WpT, b_proj, out, CC);
}

// Round 5
// 223.922 us; speedup vs baseline: 1.9140x; 1.3138x over previous
//
#include <hip/hip_runtime.h>
#include <hip/hip_bf16.h>

#define BB 4
#define TT 2048
#define CC 768
#define HH 12
#define DD 64
#define MM (BB * TT)      // 8192
#define BH (BB * HH)      // 48

typedef __bf16 bf16_t;
typedef __bf16 bf16x8 __attribute__((ext_vector_type(8)));
typedef __bf16 bf16x4 __attribute__((ext_vector_type(4)));
typedef float f32x4 __attribute__((ext_vector_type(4)));

__device__ __forceinline__ float fast_exp2(float x) {
#if __has_builtin(__builtin_amdgcn_exp2f)
    return __builtin_amdgcn_exp2f(x);
#else
    return exp2f(x);
#endif
}

__device__ __forceinline__ uint32_t pk2(float lo, float hi) {
    bf16_t l = (bf16_t)lo, h = (bf16_t)hi;
    uint16_t lu = __builtin_bit_cast(uint16_t, l);
    uint16_t hu = __builtin_bit_cast(uint16_t, h);
    return ((uint32_t)hu << 16) | lu;
}

// async global->LDS, 16B per lane. LDS dest = uniform base + lane*16 (HW rule);
// global address may scatter per-lane (we use that for the bank-swizzle).
__device__ __forceinline__ void gload_lds16(const void* g, void* l) {
    __builtin_amdgcn_global_load_lds(
        (const __attribute__((address_space(1))) uint32_t*)g,
        (__attribute__((address_space(3))) uint32_t*)l, 16, 0, 0);
}

// ---------------------------------------------------------------- convert f32 -> bf16
__global__ void cvt_f32_bf16(const float* __restrict__ in, bf16_t* __restrict__ out, int n4) {
    int tid = blockIdx.x * blockDim.x + threadIdx.x;
    if (tid >= n4) return;
    float4 v = ((const float4*)in)[tid];
    bf16x4 o;
    o[0] = (bf16_t)v.x; o[1] = (bf16_t)v.y; o[2] = (bf16_t)v.z; o[3] = (bf16_t)v.w;
    ((bf16x4*)out)[tid] = o;
}

// ---------------------------------------------------------------- transpose + convert: W[K][N] f32 -> WT[N][K] bf16
__global__ void transpose_cvt(const float* __restrict__ W, bf16_t* __restrict__ WT, int K, int N) {
    __shared__ bf16_t tile[32][33];
    int k0 = blockIdx.x * 32, n0 = blockIdx.y * 32;
    int tx = threadIdx.x, ty = threadIdx.y;   // block (32, 8)
#pragma unroll
    for (int r = 0; r < 4; ++r) {
        int kl = ty * 4 + r;
        tile[kl][tx] = (bf16_t)W[(size_t)(k0 + kl) * N + n0 + tx];
    }
    __syncthreads();
#pragma unroll
    for (int r = 0; r < 4; ++r) {
        int nl = ty * 4 + r;
        WT[(size_t)(n0 + nl) * K + k0 + tx] = tile[tx][nl];
    }
}

// ---------------------------------------------------------------- GEMM: C[M][N] = A[M][768] @ BT[N][768]^T + bias
// 128x128 tile, async global_load_lds staging (width 16), double-buffered,
// single-barrier pipelined K-loop. LDS rows 64B, chunk-rotated so frag
// ds_read_b128 is 2-way-max bank aliased (free).
template <bool OUT_BF16>
__global__ __launch_bounds__(256, 3) void gemm_bias(
        const bf16_t* __restrict__ A, const bf16_t* __restrict__ BT,
        const float* __restrict__ bias, void* __restrict__ Cout, int N) {
    const int K = 768;
    __shared__ bf16_t As[2][128 * 32];
    __shared__ bf16_t Bs[2][128 * 32];
    int tid = threadIdx.x;
    int wv = tid >> 6, lane = tid & 63, c = lane & 15, quad = lane >> 4;
    int wm = (wv >> 1) * 64, wn = (wv & 1) * 64;
    int m0 = blockIdx.x * 128, n0 = blockIdx.y * 128;

    // staging map: instr covers 16 rows (4 lanes/row); slot = lane&3 (16B col chunk)
    int srow = wv * 32 + (lane >> 2);
    int slot = lane & 3;

    auto stage = [&](int buf, int k0) {
#pragma unroll
        for (int ins = 0; ins < 2; ++ins) {
            int r = srow + ins * 16;
            int g = (slot - ((r >> 1) & 3)) & 3;     // global chunk stored at this slot
            const bf16_t* ga = A + (size_t)(m0 + r) * K + k0 + g * 8;
            const bf16_t* gb = BT + (size_t)(n0 + r) * K + k0 + g * 8;
            gload_lds16(ga, &As[buf][(wv * 32 + ins * 16) * 32]);
            gload_lds16(gb, &Bs[buf][(wv * 32 + ins * 16) * 32]);
        }
    };

    f32x4 acc[4][4] = {};
    int s_rd = (quad + ((c >> 1) & 3)) & 3;          // frag-read slot -> data chunk == quad

    const int nk = K / 32;   // 24
    stage(0, 0);
    for (int kt = 0; kt < nk; ++kt) {
        __syncthreads();                             // drains stage(kt); syncs buffer reuse
        if (kt + 1 < nk) stage((kt + 1) & 1, (kt + 1) * 32);
        int buf = kt & 1;
        bf16x8 af[4], bfr[4];
#pragma unroll
        for (int i = 0; i < 4; ++i) af[i] = *(const bf16x8*)&As[buf][(wm + i * 16 + c) * 32 + s_rd * 8];
#pragma unroll
        for (int j = 0; j < 4; ++j) bfr[j] = *(const bf16x8*)&Bs[buf][(wn + j * 16 + c) * 32 + s_rd * 8];
#pragma unroll
        for (int i = 0; i < 4; ++i)
#pragma unroll
            for (int j = 0; j < 4; ++j)
                acc[i][j] = __builtin_amdgcn_mfma_f32_16x16x32_bf16(af[i], bfr[j], acc[i][j], 0, 0, 0);
    }
#pragma unroll
    for (int j = 0; j < 4; ++j) {
        int col = n0 + wn + j * 16 + c;
        float bv = bias[col];
#pragma unroll
        for (int i = 0; i < 4; ++i) {
            int row = m0 + wm + i * 16 + quad * 4;
#pragma unroll
            for (int r = 0; r < 4; ++r) {
                float v = acc[i][j][r] + bv;
                if (OUT_BF16) ((bf16_t*)Cout)[(size_t)(row + r) * N + col] = (bf16_t)v;
                else          ((float*)Cout)[(size_t)(row + r) * N + col] = v;
            }
        }
    }
}

// ---------------------------------------------------------------- rotary: qkv -> Q,K [BH][T][64] bf16
__global__ void rotary_qk(const bf16_t* __restrict__ qkv, bf16_t* __restrict__ Q, bf16_t* __restrict__ Kc) {
    int tid = blockIdx.x * blockDim.x + threadIdx.x;   // MM*HH*32 threads
    int i = tid & 31;
    int rem = tid >> 5;
    int h = rem % HH;
    int row = rem / HH;            // b*T + t
    int b = row >> 11, t = row & (TT - 1);
    const bf16_t* base = qkv + (size_t)row * (3 * CC) + h * DD + i;
    float q1 = (float)base[0],  q2 = (float)base[32];
    float k1 = (float)base[CC], k2 = (float)base[CC + 32];
    float inv = powf(10000.0f, -(float)i * (1.0f / 32.0f));
    float fr = (float)t * inv;
    float cs = cosf(fr), sn = sinf(fr);
    const float scale = 0.125f * 1.44269504088896f;    // 1/sqrt(64) * log2(e)
    size_t o = ((size_t)(b * HH + h) * TT + t) * DD + i;
    Q[o]      = (bf16_t)((q1 * cs + q2 * sn) * scale);
    Q[o + 32] = (bf16_t)((-q1 * sn + q2 * cs) * scale);
    Kc[o]      = (bf16_t)(k1 * cs + k2 * sn);
    Kc[o + 32] = (bf16_t)(-k1 * sn + k2 * cs);
}

// ---------------------------------------------------------------- V transpose: qkv v-part -> Vt blocked [BH][T/64][64 d][64 k] bf16
__global__ void vtrans(const bf16_t* __restrict__ qkv, bf16_t* __restrict__ Vt) {
    int bh = blockIdx.x;
    int kt = blockIdx.y;           // 64-key tile index
    int t0 = kt * 64;
    int b = bh / HH, h = bh % HH;
    __shared__ bf16_t tile[64][66];
    int tx = threadIdx.x & 63, ty = threadIdx.x >> 6;
#pragma unroll
    for (int r = 0; r < 16; ++r) {
        int tl = ty * 16 + r;
        tile[tl][tx] = qkv[(size_t)(b * TT + t0 + tl) * (3 * CC) + 2 * CC + h * DD + tx];
    }
    __syncthreads();
#pragma unroll
    for (int r = 0; r < 16; ++r) {
        int dl = ty * 16 + r;
        Vt[(((size_t)bh * (TT / 64) + kt) * 64 + dl) * 64 + tx] = tile[tx][dl];
    }
}

// ---------------------------------------------------------------- flash attention, LDS-staged block-cooperative
// 768 blocks x 4 waves. Block = 128 queries of one head; waves own 32 queries.
// K/V staged per 64-key tile via global_load_lds (16 KB/tile, double-buffered),
// chunk-rotated for conflict-free ds_read_b128. Single-barrier pipelined loop.
// Math identical to R2's verified kernel (S^T=mfma(K,Q), no-max exp2 softmax,
// bpermute P-transform, O^T=mfma(V,P)).
__global__ __launch_bounds__(256, 3) void flash_attn(
        const bf16_t* __restrict__ Q, const bf16_t* __restrict__ Kc,
        const bf16_t* __restrict__ Vt, bf16_t* __restrict__ Y) {
    __shared__ bf16_t Ks[2][64 * 64];
    __shared__ bf16_t Vs[2][64 * 64];
    int blk = blockIdx.x;
    int qt = 15 - blk / BH;            // heavy query-tiles dispatch first
    int bh = blk % BH;
    int wv = threadIdx.x >> 6, lane = threadIdx.x & 63;
    int b = bh / HH, h = bh - b * HH;
    int c = lane & 15, quad = lane >> 4;
    int qb0 = qt * 128, qbw = qb0 + wv * 32;
    const bf16_t* Qg = Q + ((size_t)bh * TT + qbw) * DD;
    const bf16_t* Kg = Kc + (size_t)bh * TT * DD;
    const bf16_t* Vg = Vt + (size_t)bh * (TT / 64) * 64 * 64;   // blocked tiles

    bf16x8 qf[2][2];
#pragma unroll
    for (int s = 0; s < 2; ++s)
#pragma unroll
        for (int ch = 0; ch < 2; ++ch)
            qf[s][ch] = *(const bf16x8*)(Qg + (s * 16 + c) * DD + ch * 32 + quad * 8);

    // staging map: instr covers 8 rows (8 lanes/row); slot = lane&7 (16B chunk)
    int srow = wv * 16 + (lane >> 3);
    int slot = lane & 7;
    auto stage = [&](int buf, int kt64) {
#pragma unroll
        for (int ins = 0; ins < 2; ++ins) {
            int r = srow + ins * 8;
            int g = (slot - (r & 7)) & 7;
            gload_lds16(Kg + (size_t)(kt64 * 64 + r) * 64 + g * 8, &Ks[buf][(wv * 16 + ins * 8) * 64]);
            gload_lds16(Vg + (size_t)kt64 * 4096 + r * 64 + g * 8, &Vs[buf][(wv * 16 + ins * 8) * 64]);
        }
    };

    f32x4 O[2][4] = {};          // O^T: col=query=c, row=d=nt*16+quad*4+r
    float lsum[2] = {0.0f, 0.0f};
    int lane_lo = c + ((quad & 1) << 5);
    int lane_hi = lane_lo + 16;
    bool lowq = (quad < 2);

    int ntiles = 2 * qt + 2;
    stage(0, 0);
    for (int kt = 0; kt < ntiles; ++kt) {
        __syncthreads();                         // drains stage(kt); buffer-reuse sync
        if (kt + 1 < ntiles) stage((kt + 1) & 1, kt + 1);
        int buf = kt & 1;
#pragma unroll
        for (int t32 = 0; t32 < 2; ++t32) {
            int ks = kt * 64 + t32 * 32;
            if (ks > qbw) continue;              // beyond this wave's causal range
            bool masked = (ks == qbw);
            // frag reads from LDS (conflict-free via slot rotation)
            bf16x8 kf[2][2], vf[4];
#pragma unroll
            for (int t2 = 0; t2 < 2; ++t2)
#pragma unroll
                for (int ch = 0; ch < 2; ++ch) {
                    int row = t32 * 32 + t2 * 16 + c;
                    int sl = (ch * 4 + quad + (c & 7)) & 7;
                    kf[t2][ch] = *(const bf16x8*)&Ks[buf][row * 64 + sl * 8];
                }
#pragma unroll
            for (int nt = 0; nt < 4; ++nt) {
                int row = nt * 16 + c;
                int sl = (t32 * 4 + quad + (c & 7)) & 7;
                vf[nt] = *(const bf16x8*)&Vs[buf][row * 64 + sl * 8];
            }
            // S^T = K @ Q^T
            f32x4 st[2][2] = {};
#pragma unroll
            for (int s = 0; s < 2; ++s)
#pragma unroll
                for (int t2 = 0; t2 < 2; ++t2) {
                    st[s][t2] = __builtin_amdgcn_mfma_f32_16x16x32_bf16(kf[t2][0], qf[s][0], st[s][t2], 0, 0, 0);
                    st[s][t2] = __builtin_amdgcn_mfma_f32_16x16x32_bf16(kf[t2][1], qf[s][1], st[s][t2], 0, 0, 0);
                }
#pragma unroll
            for (int s = 0; s < 2; ++s) {
                float pv[2][4];
#pragma unroll
                for (int t2 = 0; t2 < 2; ++t2)
#pragma unroll
                    for (int r = 0; r < 4; ++r) {
                        float p = fast_exp2(st[s][t2][r]);
                        if (masked) {
                            int keyl = t2 * 16 + quad * 4 + r;
                            if (keyl > s * 16 + c) p = 0.0f;
                        }
                        pv[t2][r] = p;
                    }
                lsum[s] += ((pv[0][0] + pv[0][1]) + (pv[0][2] + pv[0][3]))
                         + ((pv[1][0] + pv[1][1]) + (pv[1][2] + pv[1][3]));
                uint32_t pk0a = pk2(pv[0][0], pv[0][1]), pk0b = pk2(pv[0][2], pv[0][3]);
                uint32_t pk1a = pk2(pv[1][0], pv[1][1]), pk1b = pk2(pv[1][2], pv[1][3]);
                union { uint32_t u[4]; bf16x8 v; } pf;
                {
                    uint32_t x0 = (uint32_t)__shfl((int)pk0a, lane_lo);
                    uint32_t y0 = (uint32_t)__shfl((int)pk1a, lane_lo);
                    pf.u[0] = lowq ? x0 : y0;
                    uint32_t x1 = (uint32_t)__shfl((int)pk0b, lane_lo);
                    uint32_t y1 = (uint32_t)__shfl((int)pk1b, lane_lo);
                    pf.u[1] = lowq ? x1 : y1;
                    uint32_t x2 = (uint32_t)__shfl((int)pk0a, lane_hi);
                    uint32_t y2 = (uint32_t)__shfl((int)pk1a, lane_hi);
                    pf.u[2] = lowq ? x2 : y2;
                    uint32_t x3 = (uint32_t)__shfl((int)pk0b, lane_hi);
                    uint32_t y3 = (uint32_t)__shfl((int)pk1b, lane_hi);
                    pf.u[3] = lowq ? x3 : y3;
                }
#pragma unroll
                for (int nt = 0; nt < 4; ++nt)
                    O[s][nt] = __builtin_amdgcn_mfma_f32_16x16x32_bf16(vf[nt], pf.v, O[s][nt], 0, 0, 0);
            }
        }
    }

    // final: reduce l across quads (queries live in c), normalize, write O^T
#pragma unroll
    for (int s = 0; s < 2; ++s) {
        float l = lsum[s];
        l += __shfl_xor(l, 16);
        l += __shfl_xor(l, 32);
        float inv_l = 1.0f / l;
        int row = b * TT + qbw + s * 16 + c;
#pragma unroll
        for (int nt = 0; nt < 4; ++nt) {
            bf16x4 ov;
#pragma unroll
            for (int r = 0; r < 4; ++r) ov[r] = (bf16_t)(O[s][nt][r] * inv_l);
            *(bf16x4*)(Y + (size_t)row * CC + h * DD + nt * 16 + quad * 4) = ov;
        }
    }
}

// ---------------------------------------------------------------- launch
extern "C" void kernel_launch(void* const* d_in, const int* in_sizes, int n_in,
                              void* d_out, int out_size, void* d_ws, size_t ws_size,
                              hipStream_t stream) {
    const float* x      = (const float*)d_in[0];
    const float* W_attn = (const float*)d_in[1];
    const float* b_attn = (const float*)d_in[2];
    const float* W_proj = (const float*)d_in[3];
    const float* b_proj = (const float*)d_in[4];
    float* out = (float*)d_out;

    unsigned char* ws = (unsigned char*)d_ws;
    size_t off = 0;
    auto alloc = [&](size_t bytes) { void* p = ws + off; off += (bytes + 255) & ~(size_t)255; return p; };
    bf16_t* xb  = (bf16_t*)alloc((size_t)MM * CC * 2);
    bf16_t* WaT = (bf16_t*)alloc((size_t)3 * CC * CC * 2);
    bf16_t* WpT = (bf16_t*)alloc((size_t)CC * CC * 2);
    bf16_t* qkv = (bf16_t*)alloc((size_t)MM * 3 * CC * 2);
    bf16_t* Qh  = (bf16_t*)alloc((size_t)BH * TT * DD * 2);
    bf16_t* Kh  = (bf16_t*)alloc((size_t)BH * TT * DD * 2);
    bf16_t* Vt  = (bf16_t*)alloc((size_t)BH * TT * DD * 2);
    bf16_t* Yb  = (bf16_t*)alloc((size_t)MM * CC * 2);

    cvt_f32_bf16<<<(MM * CC / 4 + 255) / 256, 256, 0, stream>>>(x, xb, MM * CC / 4);
    transpose_cvt<<<dim3(CC / 32, 3 * CC / 32), dim3(32, 8), 0, stream>>>(W_attn, WaT, CC, 3 * CC);
    transpose_cvt<<<dim3(CC / 32, CC / 32), dim3(32, 8), 0, stream>>>(W_proj, WpT, CC, CC);
    gemm_bias<true><<<dim3(MM / 128, 3 * CC / 128), 256, 0, stream>>>(xb, WaT, b_attn, qkv, 3 * CC);
    rotary_qk<<<(MM * HH * 32) / 256, 256, 0, stream>>>(qkv, Qh, Kh);
    vtrans<<<dim3(BH, TT / 64), 256, 0, stream>>>(qkv, Vt);
    flash_attn<<<dim3(768), 256, 0, stream>>>(Qh, Kh, Vt, Yb);
    gemm_bias<false><<<dim3(MM / 128, CC / 128), 256, 0, stream>>>(Yb, WpT, b_proj, out, CC);
}